// Round 7
// baseline (676.584 us; speedup 1.0000x reference)
//
#include <hip/hip_runtime.h>
#include <stdint.h>

// ---------------------------------------------------------------------------
// SelfAttention: LN -> QKV (bf16 MFMA GEMM) -> S=QK^T/32 -> softmax -> att*V
// B=4, N=2048, D=H=1024. Outputs: att fp32 [4,2048,2048] ++ out fp32 [4,2048,1024]
// R11: B-DIRECT + MULTI-BLOCK. R6-R10 established the plateau cause: one
//   resident block, LDS pipe serving frag-reads(2100cy)+DMA(500cy) vs MFMA
//   1536cy, barrier-lockstep => pipes alternate. Fix both sides:
//   - B fragments load global->reg (VMEM/L2 pipe, ~idle; panels L2-resident);
//     LDS holds A only. LDS reads/tile halve, DMA writes drop 40%.
//   - 128x128 tile, 256 thr (4 waves 2Mx2N), LDS 36KB -> 4 blocks/CU
//     (launch_bounds(256,4), ~115 VGPR <= 128). Independent barrier groups
//     overlap read- and MFMA-windows across blocks (m114 mechanism).
//   - R8 half-split reg pipeline + counted vmw<4> (analysis in loop comment).
//   Grids: qkv 24x64=1536, scores 16x16x4=1024 (=4/CU exact), out 8x16x4=512.
//   k_ln + k_wt merged into k_prep (one launch).
// ---------------------------------------------------------------------------

typedef __attribute__((ext_vector_type(8))) short short8;   // 8 bf16 (4 VGPRs)
typedef __attribute__((ext_vector_type(4))) float floatx4;  // MFMA acc
typedef __attribute__((ext_vector_type(4))) uint16_t u16x4;

__device__ __forceinline__ uint16_t f2bf(float f) {
    union { float f; uint32_t u; } v; v.f = f;
    uint32_t r = v.u + 0x7fffu + ((v.u >> 16) & 1u);  // RNE
    return (uint16_t)(r >> 16);
}

// async global->LDS, 16B per lane. LDS dest is wave-uniform base + lane*16.
typedef const uint32_t __attribute__((address_space(1)))* gas1_t;
typedef uint32_t __attribute__((address_space(3)))* las3_t;
__device__ __forceinline__ void gload_lds16(const uint16_t* g, uint16_t* l) {
    __builtin_amdgcn_global_load_lds((gas1_t)g, (las3_t)l, 16, 0, 0);
}

__device__ __forceinline__ void s_bar()  { asm volatile("s_barrier" ::: "memory"); }
__device__ __forceinline__ void lgkm0()  { asm volatile("s_waitcnt lgkmcnt(0)" ::: "memory"); }
template<int N> __device__ __forceinline__ void vmw() {
    asm volatile("s_waitcnt vmcnt(%0)" :: "n"(N) : "memory");
}

// ---------------------------------------------------------------------------
// gemm_bd<EPI>: C = A * Bt^T. A:[M,K] bf16 rm (LDS-staged), Bt:[N,K] bf16 rm
// (B-frags DIRECT global->reg). BM=BN=128, BK=64 (2 K-halves), 256 thr =
// 4 waves (2Mx2N), per-wave 64x64, MIW=NIW=4, acc 64 VGPR.
// LDS: 2 x 16KB A-buffers + 4KB trash = 36KB -> 4 blocks/CU.
// A staged with 16B-seg XOR swizzle (pre-swizzled global src, linear LDS,
// readers XOR the same -> 0 bank conflicts, proven R4-R9).
// Per tile: ReadsA(ks1)+LoadB(ks1) -> MFMA(ks0) -> lgkm0;bar (WAR: all waves
// done reading cur) -> STGA(te+2 -> cur) -> vmw<4>;bar -> ReadsA(next,ks0)+
// LoadB(te+1,ks0) -> MFMA(ks1).
//   vmw<4> proof: memory ops can't cross the asm (memory clobber); outstanding
//   = [<=4 B ks1][4 STGA(te+2)]; drain-to-4 retires all but STGA(te+2), so
//   stage(te+1) (older) is complete before any wave reads it after the bar.
// Overflow stages (kt>=NT) -> trash, same op count. Tail B-loads (te+1=NT)
// read in-bounds scratch garbage, never consumed.
// EPI 0: fp32 store * alpha.  EPI 1: fused-qkv bf16 + bias (3072-wide cols
//        de-interleave into q|k|v planes of 8192x1024).
// ---------------------------------------------------------------------------

#define READSA(BASE, KS)                                                  \
    _Pragma("unroll") for (int mi = 0; mi < 4; ++mi)                      \
        Af[mi][KS] = *(const short8*)((BASE) + aoff + mi * 1024 +         \
                                      ((KS) ? ksg1 : ksg0));
#define LOADB(TE, KS)                                                     \
    _Pragma("unroll") for (int ni = 0; ni < 4; ++ni)                      \
        Bf[ni][KS] = *(const short8*)(gBf + (size_t)(ni * 16) * K +       \
                                      (size_t)(TE) * 64 + (KS) * 32);
#define MFMAS(KS)                                                         \
    __builtin_amdgcn_s_setprio(1);                                        \
    _Pragma("unroll") for (int mi = 0; mi < 4; ++mi)                      \
    _Pragma("unroll") for (int ni = 0; ni < 4; ++ni)                      \
        acc[mi][ni] = __builtin_amdgcn_mfma_f32_16x16x32_bf16(            \
            Af[mi][KS], Bf[ni][KS], acc[mi][ni], 0, 0, 0);                \
    __builtin_amdgcn_s_setprio(0);

template<int EPI>
__device__ __forceinline__ void gemm_bd(
    const uint16_t* __restrict__ A, const uint16_t* __restrict__ Bt,
    const int K, const int NT, const int m0, const int n0,
    float* __restrict__ Cf, uint16_t* __restrict__ Cb, const int ldc,
    const float* __restrict__ bq, const float* __restrict__ bk,
    const float* __restrict__ bv, const float alpha)
{
    constexpr int ABUF = 128 * 64;             // 8192 elems = 16KB per buffer
    __shared__ uint16_t sm[2 * ABUF + 2048];   // 36KB total
    uint16_t* const trash = sm + 2 * ABUF;

    const int t = threadIdx.x;

    // ---- A staging: thread t covers row t>>3 (0..31, +32/op), swizzled seg
    const int srow = t >> 3;
    const int sseg = (t & 7) ^ (srow & 7);
    const uint16_t* gA = A + (size_t)(m0 + srow) * K + sseg * 8;

    auto STGA = [&](int kt, int b) {
        const bool lv = kt < NT;
        const size_t ko = (size_t)(lv ? kt : 0) * 64;
        uint16_t* const db = sm + b * ABUF + t * 8;
        uint16_t* const tr = trash + t * 8;
#pragma unroll
        for (int p = 0; p < 4; ++p)
            gload_lds16(gA + (size_t)(p * 32) * K + ko,
                        lv ? (db + p * 2048) : tr);
    };

    // ---- reader geometry: 4 waves, 2M x 2N, wave tile 64x64 ----
    const int lane = t & 63;
    const int wid  = t >> 6;
    const int wm   = wid >> 1;        // 0..1
    const int wn   = wid & 1;         // 0..1
    const int quad = lane >> 4;
    const int lrow = lane & 15;
    const int swz  = lrow & 7;
    const int ksg0 = (quad ^ swz) * 8;
    const int ksg1 = ((4 + quad) ^ swz) * 8;
    const int aoff = (wm * 64 + lrow) * 64;

    // B direct-from-global base: row n0 + wn*64 + ni*16 + lrow, k-chunk quad*8
    const uint16_t* gBf = Bt + (size_t)(n0 + wn * 64 + lrow) * K + quad * 8;

    floatx4 acc[4][4];
#pragma unroll
    for (int mi = 0; mi < 4; ++mi)
#pragma unroll
        for (int ni = 0; ni < 4; ++ni)
            acc[mi][ni] = floatx4{0.f, 0.f, 0.f, 0.f};

    short8 Af[4][2];
    short8 Bf[4][2];

    // ---- prologue: tiles 0,1 staged; wait t0; prefetch its ks0 frags ----
    STGA(0, 0);
    STGA(1, 1);
    vmw<4>();
    s_bar();
    READSA(sm, 0)
    LOADB(0, 0)

    for (int te = 0; te < NT; ++te) {
        const uint16_t* LA  = sm + (te & 1) * ABUF;
        const uint16_t* LAn = sm + ((te + 1) & 1) * ABUF;

        READSA(LA, 1)                          // ks1 A frags of te (issue)
        LOADB(te, 1)                           // ks1 B frags (global, issue)
        MFMAS(0)                               // ks0: operands prefetched
        lgkm0();                               // own A reads of LA complete
        s_bar();                               // all waves done reading (WAR)
        STGA(te + 2, te & 1);                  // re-stage current buffer
        vmw<4>();                              // stage(te+1) landed (RAW)
        s_bar();
        READSA(LAn, 0)                         // ks0 A frags of te+1 (issue)
        LOADB(te + 1, 0)                       // ks0 B frags of te+1 (issue)
        MFMAS(1)                               // ks1 of te
    }

    vmw<0>();  // drain trailing trash stages

    // ---- epilogue: C/D layout col=lane&15, row=quad*4+reg [m89/m91] ----
    const int rbase = m0 + wm * 64 + quad * 4;
    const int cbase = n0 + wn * 64 + lrow;

    if constexpr (EPI == 1) {
        float bc[4];
#pragma unroll
        for (int ni = 0; ni < 4; ++ni) {
            const int col = cbase + ni * 16;
            const int z = col >> 10;
            const float* bp = (z == 0) ? bq : ((z == 1) ? bk : bv);
            bc[ni] = bp[col & 1023];
        }
#pragma unroll
        for (int mi = 0; mi < 4; ++mi) {
#pragma unroll
            for (int ni = 0; ni < 4; ++ni) {
                const int row = rbase + mi * 16;
                const int col = cbase + ni * 16;
                const int z = col >> 10, h = col & 1023;
#pragma unroll
                for (int r = 0; r < 4; ++r)
                    Cb[(size_t)z * 8388608 + (size_t)(row + r) * 1024 + h] =
                        f2bf(acc[mi][ni][r] + bc[ni]);
            }
        }
    } else {
#pragma unroll
        for (int mi = 0; mi < 4; ++mi) {
#pragma unroll
            for (int ni = 0; ni < 4; ++ni) {
                const int row = rbase + mi * 16;
                const int col = cbase + ni * 16;
#pragma unroll
                for (int r = 0; r < 4; ++r)
                    Cf[(size_t)(row + r) * ldc + col] = acc[mi][ni][r] * alpha;
            }
        }
    }
}

// q|k|v = xn @ [wq|wk|wv]^T + bias, one GEMM M=8192 N=3072 K=1024.
__global__ __launch_bounds__(256, 4) void k_qkv(
    const uint16_t* __restrict__ xn, const uint16_t* __restrict__ wt,
    const float* __restrict__ bq, const float* __restrict__ bk,
    const float* __restrict__ bv, uint16_t* __restrict__ qkv)
{
    // grid (24, 64) = 1536 blocks; bijective XCD swizzle (1536 % 8 == 0)
    const int flat = blockIdx.y * 24 + blockIdx.x;
    const int s = (flat & 7) * 192 + (flat >> 3);
    const int bx = s % 24, by = s / 24;
    gemm_bd<1>(xn, wt, 1024, 16, by * 128, bx * 128,
               nullptr, qkv, 0, bq, bk, bv, 0.f);
}

// S = q @ k^T * (1/32), fp32 into d_out att region. grid 1024 = 4/CU exact.
__global__ __launch_bounds__(256, 4) void k_scores(
    const uint16_t* __restrict__ q, const uint16_t* __restrict__ k,
    float* __restrict__ S)
{
    const int flat = (blockIdx.z * 16 + blockIdx.y) * 16 + blockIdx.x;
    const int s = (flat & 7) * 128 + (flat >> 3);       // 1024-bijective
    const int x = s & 15, y = (s >> 4) & 15, z = s >> 8;
    gemm_bd<0>(q + (size_t)z * 2048 * 1024, k + (size_t)z * 2048 * 1024,
               1024, 16, y * 128, x * 128,
               S + (size_t)z * 2048 * 2048, nullptr, 2048,
               nullptr, nullptr, nullptr, 0.03125f);
}

// out = att_bf16 @ vt^T, fp32. K=2048, grid 512 = 2/CU.
__global__ __launch_bounds__(256, 4) void k_out(
    const uint16_t* __restrict__ attb, const uint16_t* __restrict__ vt,
    float* __restrict__ out)
{
    const int flat = (blockIdx.z * 16 + blockIdx.y) * 8 + blockIdx.x;
    const int s = (flat & 7) * 64 + (flat >> 3);        // 512-bijective
    const int x = s & 7, y = (s >> 3) & 15, z = s >> 7;
    gemm_bd<0>(attb + (size_t)z * 2048 * 2048, vt + (size_t)z * 1024 * 2048,
               2048, 32, y * 128, x * 128,
               out + (size_t)z * 2048 * 1024, nullptr, 1024,
               nullptr, nullptr, nullptr, 1.0f);
}

// ---------------------------------------------------------------------------
// k_prep: blocks [0,8192) = LayerNorm rows x[8192][1024] -> bf16 xn;
//         blocks [8192,11264) = weight transpose+cast fp32 -> bf16 wt[h][d].
// ---------------------------------------------------------------------------
__global__ __launch_bounds__(256) void k_prep(
    const float* __restrict__ x, const float* __restrict__ lw,
    const float* __restrict__ lb, uint16_t* __restrict__ xn,
    const float* __restrict__ wq, const float* __restrict__ wk,
    const float* __restrict__ wv, uint16_t* __restrict__ wt)
{
    const int t = threadIdx.x;
    if (blockIdx.x < 8192) {
        const int row = blockIdx.x;
        const float* xr = x + (size_t)row * 1024;
        const float4 xv = ((const float4*)xr)[t];
        float s  = xv.x + xv.y + xv.z + xv.w;
        float s2 = xv.x * xv.x + xv.y * xv.y + xv.z * xv.z + xv.w * xv.w;
#pragma unroll
        for (int off = 32; off > 0; off >>= 1) {
            s  += __shfl_xor(s, off);
            s2 += __shfl_xor(s2, off);
        }
        __shared__ float ps[4], ps2[4];
        const int w = t >> 6, lane = t & 63;
        if (lane == 0) { ps[w] = s; ps2[w] = s2; }
        __syncthreads();
        s  = ps[0] + ps[1] + ps[2] + ps[3];
        s2 = ps2[0] + ps2[1] + ps2[2] + ps2[3];
        const float mu  = s * (1.f / 1024.f);
        const float var = s2 * (1.f / 1024.f) - mu * mu;
        const float rs  = rsqrtf(var + 1e-5f);
        const float4 wv4 = ((const float4*)lw)[t];
        const float4 bv4 = ((const float4*)lb)[t];
        u16x4 o;
        o.x = f2bf((xv.x - mu) * rs * wv4.x + bv4.x);
        o.y = f2bf((xv.y - mu) * rs * wv4.y + bv4.y);
        o.z = f2bf((xv.z - mu) * rs * wv4.z + bv4.z);
        o.w = f2bf((xv.w - mu) * rs * wv4.w + bv4.w);
        ((u16x4*)(xn + (size_t)row * 1024))[t] = o;
    } else {
        __shared__ float tile[32][33];
        const int bid = blockIdx.x - 8192;
        const int z = bid >> 10;                 // 0..2
        const int rem = bid & 1023;
        const int c0 = (rem & 31) * 32, r0 = (rem >> 5) * 32;
        const float* W = (z == 0) ? wq : ((z == 1) ? wk : wv);
        uint16_t* T = wt + (size_t)z * 1024 * 1024;
        const int tx = t & 31, ty = t >> 5;      // (32,8)
#pragma unroll
        for (int i = 0; i < 4; i++)
            tile[ty + 8 * i][tx] = W[(size_t)(r0 + ty + 8 * i) * 1024 + c0 + tx];
        __syncthreads();
#pragma unroll
        for (int i = 0; i < 4; i++)
            T[(size_t)(c0 + ty + 8 * i) * 1024 + r0 + tx] = f2bf(tile[tx][ty + 8 * i]);
    }
}

// ---------------------------------------------------------------------------
// Transpose v bf16 [2048][1024] -> vt [1024][2048] per batch.
// ---------------------------------------------------------------------------
__global__ __launch_bounds__(256) void k_vt(
    const uint16_t* __restrict__ v, uint16_t* __restrict__ vt)
{
    __shared__ uint16_t tile[64][68];
    const int b = blockIdx.z;
    const uint16_t* V = v + (size_t)b * 2048 * 1024;
    uint16_t* T = vt + (size_t)b * 1024 * 2048;
    const int h0 = blockIdx.x * 64, t0 = blockIdx.y * 64;
    const int t = threadIdx.x;
    const int rr = t >> 4;
    const int cc = (t & 15) * 4;
#pragma unroll
    for (int i = 0; i < 4; i++) {
        const int tok = rr + 16 * i;
        *(u16x4*)&tile[tok][cc] =
            *(const u16x4*)&V[(size_t)(t0 + tok) * 1024 + h0 + cc];
    }
    __syncthreads();
#pragma unroll
    for (int i = 0; i < 4; i++) {
        const int h = rr + 16 * i;
        u16x4 o;
        o.x = tile[cc + 0][h];
        o.y = tile[cc + 1][h];
        o.z = tile[cc + 2][h];
        o.w = tile[cc + 3][h];
        *(u16x4*)&T[(size_t)(h0 + h) * 2048 + t0 + cc] = o;
    }
}

// ---------------------------------------------------------------------------
// Row softmax over S[8192][2048] fp32 (in place) + bf16 copy for the PV GEMM
// ---------------------------------------------------------------------------
__global__ __launch_bounds__(256) void k_softmax(
    float* __restrict__ S, uint16_t* __restrict__ attb)
{
    const size_t row = blockIdx.x;
    float* p = S + row * 2048;
    const int t = threadIdx.x;
    float4 a = ((float4*)p)[2 * t];
    float4 b = ((float4*)p)[2 * t + 1];
    float m = fmaxf(fmaxf(fmaxf(a.x, a.y), fmaxf(a.z, a.w)),
                    fmaxf(fmaxf(b.x, b.y), fmaxf(b.z, b.w)));
#pragma unroll
    for (int off = 32; off > 0; off >>= 1) m = fmaxf(m, __shfl_xor(m, off));
    __shared__ float pm[4], pl[4];
    const int w = t >> 6, lane = t & 63;
    if (lane == 0) pm[w] = m;
    __syncthreads();
    m = fmaxf(fmaxf(pm[0], pm[1]), fmaxf(pm[2], pm[3]));

    a.x = __expf(a.x - m); a.y = __expf(a.y - m);
    a.z = __expf(a.z - m); a.w = __expf(a.w - m);
    b.x = __expf(b.x - m); b.y = __expf(b.y - m);
    b.z = __expf(b.z - m); b.w = __expf(b.w - m);
    float s = a.x + a.y + a.z + a.w + b.x + b.y + b.z + b.w;
#pragma unroll
    for (int off = 32; off > 0; off >>= 1) s += __shfl_xor(s, off);
    if (lane == 0) pl[w] = s;
    __syncthreads();
    s = pl[0] + pl[1] + pl[2] + pl[3];
    const float inv = 1.f / s;

    a.x *= inv; a.y *= inv; a.z *= inv; a.w *= inv;
    b.x *= inv; b.y *= inv; b.z *= inv; b.w *= inv;
    ((float4*)p)[2 * t]     = a;
    ((float4*)p)[2 * t + 1] = b;

    uint16_t* q = attb + row * 2048 + t * 8;
    u16x4 o0, o1;
    o0.x = f2bf(a.x); o0.y = f2bf(a.y); o0.z = f2bf(a.z); o0.w = f2bf(a.w);
    o1.x = f2bf(b.x); o1.y = f2bf(b.y); o1.z = f2bf(b.z); o1.w = f2bf(b.w);
    ((u16x4*)q)[0] = o0;
    ((u16x4*)q)[1] = o1;
}

// ---------------------------------------------------------------------------
extern "C" void kernel_launch(void* const* d_in, const int* in_sizes, int n_in,
                              void* d_out, int out_size, void* d_ws, size_t ws_size,
                              hipStream_t stream)
{
    const float* x  = (const float*)d_in[0];
    const float* wq = (const float*)d_in[1];
    const float* bq = (const float*)d_in[2];
    const float* wk = (const float*)d_in[3];
    const float* bk = (const float*)d_in[4];
    const float* wv = (const float*)d_in[5];
    const float* bv = (const float*)d_in[6];
    const float* lw = (const float*)d_in[7];
    const float* lb = (const float*)d_in[8];

    float* att = (float*)d_out;                         // [4][2048][2048] = 64 MB
    float* out = (float*)d_out + (size_t)16777216;      // [4][2048][1024] = 32 MB

    // Scratch inside d_out's att region (dead until k_scores writes all of it):
    uint16_t* xn = (uint16_t*)d_out;                    // 8,388,608 elems (16.8 MB)
    uint16_t* wt = (uint16_t*)d_out + (size_t)8388608;  // 3,145,728 elems (6.3 MB)

    // ws layout (uint16 elems), exactly q+k+v = 25,165,824 elems = 50,331,648 B:
    uint16_t* ws   = (uint16_t*)d_ws;
    uint16_t* q    = ws;
    uint16_t* k    = ws + (size_t)8388608;
    uint16_t* v    = ws + (size_t)2 * 8388608;
    uint16_t* vt   = ws;                                // overlays dead q
    uint16_t* attb = ws + (size_t)8388608;              // overlays dead k+v
    uint16_t* qkv  = q;

    if (ws_size < (size_t)50331648) return;  // OOB guard: fail clean, not crash

    k_prep<<<8192 + 3072, 256, 0, stream>>>(x, lw, lb, xn, wq, wk, wv, wt);
    k_qkv<<<dim3(24, 64), 256, 0, stream>>>(xn, wt, bq, bk, bv, qkv);
    k_scores<<<dim3(16, 16, 4), 256, 0, stream>>>(q, k, att);   // frees q,k
    k_vt<<<dim3(16, 32, 4), 256, 0, stream>>>(v, vt);           // vt over dead q
    k_softmax<<<8192, 256, 0, stream>>>(att, attb);             // attb over dead k+v
    k_out<<<dim3(8, 16, 4), 256, 0, stream>>>(attb, vt, out);
}

// Round 8
// 316.583 us; speedup vs baseline: 2.1371x; 2.1371x over previous
//
#include <hip/hip_runtime.h>
#include <stdint.h>

// ---------------------------------------------------------------------------
// SelfAttention: LN -> QKV (bf16 MFMA GEMM) -> S=QK^T/32 -> softmax -> att*V
// B=4, N=2048, D=H=1024. Outputs: att fp32 [4,2048,2048] ++ out fp32 [4,2048,1024]
// R12: consolidation. GEMM cores = R8 exactly (best measured: 306.7us).
//   R10/R11 proved fat-wave + B-direct dead ends (VGPR file / spill bound).
//   Structural wins only:
//   - k_vt DELETED: V-transpose fused into k_qkv epilogue. z==2 frags stash
//     into the dead LDS GEMM buffers as [192][260] (padded, conflict-free),
//     then written as coalesced vt[h][tok] rows. Saves a 32MB round-trip
//     kernel + launch gap; frees v so attb moves to ws[0..16M).
//   - k_ln + k_wt merged into k_prep (one launch, proven R11).
//   Launches 7 -> 5: prep, qkv, scores, softmax, out.
// ---------------------------------------------------------------------------

typedef __attribute__((ext_vector_type(8))) short short8;   // 8 bf16 (4 VGPRs)
typedef __attribute__((ext_vector_type(4))) float floatx4;  // MFMA acc
typedef __attribute__((ext_vector_type(4))) uint16_t u16x4;

__device__ __forceinline__ uint16_t f2bf(float f) {
    union { float f; uint32_t u; } v; v.f = f;
    uint32_t r = v.u + 0x7fffu + ((v.u >> 16) & 1u);  // RNE
    return (uint16_t)(r >> 16);
}

// async global->LDS, 16B per lane. LDS dest is wave-uniform base + lane*16.
typedef const uint32_t __attribute__((address_space(1)))* gas1_t;
typedef uint32_t __attribute__((address_space(3)))* las3_t;
__device__ __forceinline__ void gload_lds16(const uint16_t* g, uint16_t* l) {
    __builtin_amdgcn_global_load_lds((gas1_t)g, (las3_t)l, 16, 0, 0);
}

__device__ __forceinline__ void s_bar()  { asm volatile("s_barrier" ::: "memory"); }
__device__ __forceinline__ void lgkm0()  { asm volatile("s_waitcnt lgkmcnt(0)" ::: "memory"); }
template<int N> __device__ __forceinline__ void vmw() {
    asm volatile("s_waitcnt vmcnt(%0)" :: "n"(N) : "memory");
}

// ---------------------------------------------------------------------------
// gemm_core<BN,EPI>: C = A * Bt^T. A:[M,K] bf16 rm, Bt:[N,K] bf16 rm. BM=256.
// 512 thr = 8 waves. BN=192: 2Mx4N waves (per-wave 128x48), 2-buf LDS.
// BN=128: 4Mx2N waves (per-wave 64x64), 3-buf LDS, 1 barrier/tile.
// BK=64 split into two K-halves ks0/ks1 (ksg0/ksg1 swizzled segs).
// 16B-seg XOR swizzle (phys_seg = seg ^ (row&7)) via pre-swizzled global src +
// linear LDS dest; readers XOR the same -> 0 bank conflicts (proven R4-R9).
// Hazards per tile: WAR = lgkm0 (+bar for 2-buf) before re-staging a read
// buffer; RAW = counted vmw<OPS> + bar before reading next tile's buffer.
// EPI 0: fp32 store * alpha.  EPI 1: fused-qkv bf16 + bias; z0/z1 cols store
//        to q|k planes; z2 cols stash->LDS-transpose->coalesced vt[h][tok].
// ---------------------------------------------------------------------------

#define READS(BASE, KS)                                                   \
    { const uint16_t* LBp = (BASE) + ABUF;                                \
      _Pragma("unroll") for (int mi = 0; mi < MIW; ++mi)                  \
          Af[mi][KS] = *(const short8*)((BASE) + aoff + mi * 1024 +       \
                                        ((KS) ? ksg1 : ksg0));            \
      _Pragma("unroll") for (int ni = 0; ni < NIW; ++ni)                  \
          Bf[ni][KS] = *(const short8*)(LBp + boff + ni * 1024 +          \
                                        ((KS) ? ksg1 : ksg0)); }

#define MFMAS(KS)                                                         \
    __builtin_amdgcn_s_setprio(1);                                        \
    _Pragma("unroll") for (int mi = 0; mi < MIW; ++mi)                    \
    _Pragma("unroll") for (int ni = 0; ni < NIW; ++ni)                    \
        acc[mi][ni] = __builtin_amdgcn_mfma_f32_16x16x32_bf16(            \
            Af[mi][KS], Bf[ni][KS], acc[mi][ni], 0, 0, 0);                \
    __builtin_amdgcn_s_setprio(0);

template<int BN, int EPI>
__device__ __forceinline__ void gemm_core(
    const uint16_t* __restrict__ A, const uint16_t* __restrict__ Bt,
    const int K, const int NT, const int m0, const int n0,
    float* __restrict__ Cf, uint16_t* __restrict__ Cb, const int ldc,
    const float* __restrict__ bq, const float* __restrict__ bk,
    const float* __restrict__ bv, const float alpha,
    uint16_t* __restrict__ vtp)
{
    constexpr int ABUF  = 256 * 64;            // 16384 elems
    constexpr int BP    = BN / 64;             // B stage passes (3,2)
    constexpr int BBUF  = BN * 64;
    constexpr int BUFSZ = ABUF + BBUF;
    constexpr int OPS   = 4 + BP;              // stage ops per K-tile
    constexpr int NBUF  = (BN == 128) ? 3 : 2;
    constexpr int WAVES_N = (BN == 128) ? 2 : 4;
    constexpr int MIW  = (BN == 128) ? 4 : 8;  // mi frags per wave
    constexpr int NIW  = BN / (16 * WAVES_N);  // ni frags (4 or 3)
    __shared__ uint16_t sm[NBUF * BUFSZ + 4096];
    uint16_t* const trash = sm + NBUF * BUFSZ;

    const int t = threadIdx.x;

    // ---- staging geometry ----
    const int srow = t >> 3;                  // 0..63
    const int sseg = (t & 7) ^ (srow & 7);    // pre-swizzled global 16B-seg
    const uint16_t* gA = A + (size_t)(m0 + srow) * K + sseg * 8;
    const uint16_t* gB = Bt + (size_t)(n0 + srow) * K + sseg * 8;

    // stage one whole K-tile (OPS async gloads); kt>=NT -> trash (never read)
    auto STGALL = [&](int kt, int bi) {
        const int live = kt < NT;
        const size_t ko = (size_t)(live ? kt : 0) * 64;
        uint16_t* const db = sm + bi * BUFSZ + t * 8;
        uint16_t* const tr = trash + t * 8;
#pragma unroll
        for (int p = 0; p < 4; ++p)
            gload_lds16(gA + (size_t)(p * 64) * K + ko,
                        live ? (db + p * 4096) : tr);
#pragma unroll
        for (int p = 0; p < BP; ++p)
            gload_lds16(gB + (size_t)(p * 64) * K + ko,
                        live ? (db + ABUF + p * 4096) : tr);
    };

    // ---- reader geometry ----
    const int lane = t & 63;
    const int wid  = t >> 6;
    const int wm   = wid / WAVES_N;
    const int wn   = wid % WAVES_N;
    const int quad = lane >> 4;
    const int lrow = lane & 15;
    const int swz  = lrow & 7;
    const int ksg0 = (quad ^ swz) * 8;
    const int ksg1 = ((4 + quad) ^ swz) * 8;
    const int aoff = (wm * (16 * MIW) + lrow) * 64;
    const int boff = (wn * (16 * NIW) + lrow) * 64;

    floatx4 acc[MIW][NIW];
#pragma unroll
    for (int mi = 0; mi < MIW; ++mi)
#pragma unroll
        for (int ni = 0; ni < NIW; ++ni)
            acc[mi][ni] = floatx4{0.f, 0.f, 0.f, 0.f};

    short8 Af[MIW][2];
    short8 Bf[NIW][2];

    // ---- prologue: tiles 0,1 staged; wait tile0; prefetch its ks0 frags ----
    STGALL(0, 0);
    STGALL(1, 1);
    vmw<OPS>();
    s_bar();
    READS(sm, 0);

    int bcur = 0, bstage = 2;  // BN==128 3-buffer rotation only
    for (int te = 0; te < NT; ++te) {
        const uint16_t* LA;
        const uint16_t* LAn;
        if constexpr (BN == 128) {
            LA = sm + bcur * BUFSZ;
            const int bnext = (bcur == 2) ? 0 : bcur + 1;
            LAn = sm + bnext * BUFSZ;
            STGALL(te + 2, bstage);            // free buffer: no WAR wait
        } else {
            LA  = sm + (te & 1) * BUFSZ;
            LAn = sm + ((te + 1) & 1) * BUFSZ;
        }

        READS(LA, 1);                          // ks1 frags of te (issue only)
        MFMAS(0);                              // ks0: operands prefetched
        lgkm0();                               // own reads of LA complete (WAR)
        if constexpr (BN != 128) {
            s_bar();                           // all waves done reading bi
            STGALL(te + 2, te & 1);            // re-stage current buffer
        }
        vmw<OPS>();                            // te+1's stages landed (RAW)
        s_bar();
        READS(LAn, 0);                         // ks0 frags of te+1 (issue only)
        MFMAS(1);                              // ks1 of te; covers the reads

        if constexpr (BN == 128) {
            bcur   = (bcur == 2) ? 0 : bcur + 1;
            bstage = (bstage == 2) ? 0 : bstage + 1;
        }
    }

    vmw<0>();  // drain clamped trash stages

    // ---- epilogue: C/D layout col=lane&15, row=quad*4+reg [m89/m91] ----
    const int rbase = m0 + wm * (16 * MIW) + quad * 4;
    const int cbase = n0 + wn * (16 * NIW) + lrow;

    if constexpr (EPI == 1) {
        // fused-qkv epilogue with V-transpose fusion.
        // z0/z1 frags -> plain bf16 stores into q|k planes.
        // z2 frags -> stash into dead LDS as [BN][260] (260-pad: 8B-aligned
        // rows, banks stride 2 -> conflict-free), then coalesced vt writes.
        float bc[NIW];
#pragma unroll
        for (int ni = 0; ni < NIW; ++ni) {
            const int col = cbase + ni * 16;
            const int z = col >> 10;
            const float* bp = (z == 0) ? bq : ((z == 1) ? bk : bv);
            bc[ni] = bp[col & 1023];
        }
        uint16_t* const stash = sm;            // [BN][260], 192*260 <= 61440
#pragma unroll
        for (int mi = 0; mi < MIW; ++mi) {
#pragma unroll
            for (int ni = 0; ni < NIW; ++ni) {
                const int col = cbase + ni * 16;
                const int z = col >> 10;
                if (z == 2) {
                    const int lr = wm * (16 * MIW) + quad * 4 + mi * 16;
#pragma unroll
                    for (int r = 0; r < 4; ++r)
                        stash[(col - n0) * 260 + lr + r] =
                            f2bf(acc[mi][ni][r] + bc[ni]);
                } else {
                    const int row = rbase + mi * 16;
                    const int h = col & 1023;
#pragma unroll
                    for (int r = 0; r < 4; ++r)
                        Cb[(size_t)z * 8388608 + (size_t)(row + r) * 1024 + h] =
                            f2bf(acc[mi][ni][r] + bc[ni]);
                }
            }
        }
        if (n0 + BN > 2048) {                  // block-uniform: has z2 cols
            lgkm0();                           // stash writes visible
            s_bar();
            const int b  = m0 >> 11;           // batch (BM=256 | 2048)
            const int t0 = m0 & 2047;          // token base
            for (int cl = wid; cl < BN; cl += 8) {
                const int col = n0 + cl;
                if (col >= 2048) {
                    const u16x4 vv =
                        *(const u16x4*)&stash[cl * 260 + lane * 4];
                    *(u16x4*)&vtp[(size_t)b * 2097152 +
                                  (size_t)(col - 2048) * 2048 + t0 + lane * 4] = vv;
                }
            }
        }
    } else {
#pragma unroll
        for (int mi = 0; mi < MIW; ++mi) {
#pragma unroll
            for (int ni = 0; ni < NIW; ++ni) {
                const int row = rbase + mi * 16;
                const int col = cbase + ni * 16;
#pragma unroll
                for (int r = 0; r < 4; ++r)
                    Cf[(size_t)(row + r) * ldc + col] = acc[mi][ni][r] * alpha;
            }
        }
    }
}

// q|k = xn @ [wq|wk]^T + bias planes; v-columns transposed directly to vt.
__global__ __launch_bounds__(512, 2) void k_qkv(
    const uint16_t* __restrict__ xn, const uint16_t* __restrict__ wt,
    const float* __restrict__ bq, const float* __restrict__ bk,
    const float* __restrict__ bv, uint16_t* __restrict__ qk,
    uint16_t* __restrict__ vt)
{
    // grid (16, 32) = 512 blocks -> 2 uniform rounds; bijective XCD swizzle
    const int flat = blockIdx.y * 16 + blockIdx.x;
    const int s = (flat & 7) * 64 + (flat >> 3);
    const int bx = s & 15, by = s >> 4;
    gemm_core<192, 1>(xn, wt, 1024, 16, by * 256, bx * 192,
                      nullptr, qk, 0, bq, bk, bv, 0.f, vt);
}

// S = q @ k^T * (1/32), fp32 into d_out att region. BN=128, 512 blocks.
__global__ __launch_bounds__(512, 2) void k_scores(
    const uint16_t* __restrict__ q, const uint16_t* __restrict__ k,
    float* __restrict__ S)
{
    const int flat = (blockIdx.z * 8 + blockIdx.y) * 16 + blockIdx.x;
    const int s = (flat & 7) * 64 + (flat >> 3);        // 512-bijective
    const int x = s & 15, y = (s >> 4) & 7, z = s >> 7;
    gemm_core<128, 0>(q + (size_t)z * 2048 * 1024, k + (size_t)z * 2048 * 1024,
                      1024, 16, y * 256, x * 128,
                      S + (size_t)z * 2048 * 2048, nullptr, 2048,
                      nullptr, nullptr, nullptr, 0.03125f, nullptr);
}

// out = att_bf16 @ vt^T, fp32. BN=128, K=2048, grid 256 = 1/CU, 3-buf LDS.
__global__ __launch_bounds__(512, 2) void k_out(
    const uint16_t* __restrict__ attb, const uint16_t* __restrict__ vt,
    float* __restrict__ out)
{
    const int flat = blockIdx.z * 64 + blockIdx.y * 8 + blockIdx.x;
    const int s = (flat & 7) * 32 + (flat >> 3);        // 256-bijective
    const int z = s >> 6, y = (s >> 3) & 7, x = s & 7;
    gemm_core<128, 0>(attb + (size_t)z * 2048 * 2048, vt + (size_t)z * 1024 * 2048,
                      2048, 32, y * 256, x * 128,
                      out + (size_t)z * 2048 * 1024, nullptr, 1024,
                      nullptr, nullptr, nullptr, 1.0f, nullptr);
}

// ---------------------------------------------------------------------------
// k_prep: blocks [0,8192) = LayerNorm rows x[8192][1024] -> bf16 xn;
//         blocks [8192,11264) = weight transpose+cast fp32 -> bf16 wt[h][d].
// ---------------------------------------------------------------------------
__global__ __launch_bounds__(256) void k_prep(
    const float* __restrict__ x, const float* __restrict__ lw,
    const float* __restrict__ lb, uint16_t* __restrict__ xn,
    const float* __restrict__ wq, const float* __restrict__ wk,
    const float* __restrict__ wv, uint16_t* __restrict__ wt)
{
    const int t = threadIdx.x;
    if (blockIdx.x < 8192) {
        const int row = blockIdx.x;
        const float* xr = x + (size_t)row * 1024;
        const float4 xv = ((const float4*)xr)[t];
        float s  = xv.x + xv.y + xv.z + xv.w;
        float s2 = xv.x * xv.x + xv.y * xv.y + xv.z * xv.z + xv.w * xv.w;
#pragma unroll
        for (int off = 32; off > 0; off >>= 1) {
            s  += __shfl_xor(s, off);
            s2 += __shfl_xor(s2, off);
        }
        __shared__ float ps[4], ps2[4];
        const int w = t >> 6, lane = t & 63;
        if (lane == 0) { ps[w] = s; ps2[w] = s2; }
        __syncthreads();
        s  = ps[0] + ps[1] + ps[2] + ps[3];
        s2 = ps2[0] + ps2[1] + ps2[2] + ps2[3];
        const float mu  = s * (1.f / 1024.f);
        const float var = s2 * (1.f / 1024.f) - mu * mu;
        const float rs  = rsqrtf(var + 1e-5f);
        const float4 wv4 = ((const float4*)lw)[t];
        const float4 bv4 = ((const float4*)lb)[t];
        u16x4 o;
        o.x = f2bf((xv.x - mu) * rs * wv4.x + bv4.x);
        o.y = f2bf((xv.y - mu) * rs * wv4.y + bv4.y);
        o.z = f2bf((xv.z - mu) * rs * wv4.z + bv4.z);
        o.w = f2bf((xv.w - mu) * rs * wv4.w + bv4.w);
        ((u16x4*)(xn + (size_t)row * 1024))[t] = o;
    } else {
        __shared__ float tile[32][33];
        const int bid = blockIdx.x - 8192;
        const int z = bid >> 10;                 // 0..2
        const int rem = bid & 1023;
        const int c0 = (rem & 31) * 32, r0 = (rem >> 5) * 32;
        const float* W = (z == 0) ? wq : ((z == 1) ? wk : wv);
        uint16_t* T = wt + (size_t)z * 1024 * 1024;
        const int tx = t & 31, ty = t >> 5;      // (32,8)
#pragma unroll
        for (int i = 0; i < 4; i++)
            tile[ty + 8 * i][tx] = W[(size_t)(r0 + ty + 8 * i) * 1024 + c0 + tx];
        __syncthreads();
#pragma unroll
        for (int i = 0; i < 4; i++)
            T[(size_t)(c0 + ty + 8 * i) * 1024 + r0 + tx] = f2bf(tile[tx][ty + 8 * i]);
    }
}

// ---------------------------------------------------------------------------
// Row softmax over S[8192][2048] fp32 (in place) + bf16 copy for the PV GEMM
// ---------------------------------------------------------------------------
__global__ __launch_bounds__(256) void k_softmax(
    float* __restrict__ S, uint16_t* __restrict__ attb)
{
    const size_t row = blockIdx.x;
    float* p = S + row * 2048;
    const int t = threadIdx.x;
    float4 a = ((float4*)p)[2 * t];
    float4 b = ((float4*)p)[2 * t + 1];
    float m = fmaxf(fmaxf(fmaxf(a.x, a.y), fmaxf(a.z, a.w)),
                    fmaxf(fmaxf(b.x, b.y), fmaxf(b.z, b.w)));
#pragma unroll
    for (int off = 32; off > 0; off >>= 1) m = fmaxf(m, __shfl_xor(m, off));
    __shared__ float pm[4], pl[4];
    const int w = t >> 6, lane = t & 63;
    if (lane == 0) pm[w] = m;
    __syncthreads();
    m = fmaxf(fmaxf(pm[0], pm[1]), fmaxf(pm[2], pm[3]));

    a.x = __expf(a.x - m); a.y = __expf(a.y - m);
    a.z = __expf(a.z - m); a.w = __expf(a.w - m);
    b.x = __expf(b.x - m); b.y = __expf(b.y - m);
    b.z = __expf(b.z - m); b.w = __expf(b.w - m);
    float s = a.x + a.y + a.z + a.w + b.x + b.y + b.z + b.w;
#pragma unroll
    for (int off = 32; off > 0; off >>= 1) s += __shfl_xor(s, off);
    if (lane == 0) pl[w] = s;
    __syncthreads();
    s = pl[0] + pl[1] + pl[2] + pl[3];
    const float inv = 1.f / s;

    a.x *= inv; a.y *= inv; a.z *= inv; a.w *= inv;
    b.x *= inv; b.y *= inv; b.z *= inv; b.w *= inv;
    ((float4*)p)[2 * t]     = a;
    ((float4*)p)[2 * t + 1] = b;

    uint16_t* q = attb + row * 2048 + t * 8;
    u16x4 o0, o1;
    o0.x = f2bf(a.x); o0.y = f2bf(a.y); o0.z = f2bf(a.z); o0.w = f2bf(a.w);
    o1.x = f2bf(b.x); o1.y = f2bf(b.y); o1.z = f2bf(b.z); o1.w = f2bf(b.w);
    ((u16x4*)q)[0] = o0;
    ((u16x4*)q)[1] = o1;
}

// ---------------------------------------------------------------------------
extern "C" void kernel_launch(void* const* d_in, const int* in_sizes, int n_in,
                              void* d_out, int out_size, void* d_ws, size_t ws_size,
                              hipStream_t stream)
{
    const float* x  = (const float*)d_in[0];
    const float* wq = (const float*)d_in[1];
    const float* bq = (const float*)d_in[2];
    const float* wk = (const float*)d_in[3];
    const float* bk = (const float*)d_in[4];
    const float* wv = (const float*)d_in[5];
    const float* bv = (const float*)d_in[6];
    const float* lw = (const float*)d_in[7];
    const float* lb = (const float*)d_in[8];

    float* att = (float*)d_out;                         // [4][2048][2048] = 64 MB
    float* out = (float*)d_out + (size_t)16777216;      // [4][2048][1024] = 32 MB

    // Scratch inside d_out's att region (dead until k_scores writes all of it):
    uint16_t* xn = (uint16_t*)d_out;                    // 8,388,608 elems (16.8 MB)
    uint16_t* wt = (uint16_t*)d_out + (size_t)8388608;  // 3,145,728 elems (6.3 MB)

    // ws layout (uint16 elems), 25,165,824 elems = 50,331,648 B:
    //   [0, 8M)    q    -> dead after k_scores ┐
    //   [8M, 16M)  k    -> dead after k_scores ┴-> attb (16M elems)
    //   [16M, 24M) vt   (written transposed by k_qkv; live until k_out)
    uint16_t* ws   = (uint16_t*)d_ws;
    uint16_t* q    = ws;
    uint16_t* k    = ws + (size_t)8388608;
    uint16_t* vt   = ws + (size_t)2 * 8388608;
    uint16_t* attb = ws;                                // overlays dead q+k

    if (ws_size < (size_t)50331648) return;  // OOB guard: fail clean, not crash

    k_prep<<<8192 + 3072, 256, 0, stream>>>(x, lw, lb, xn, wq, wk, wv, wt);
    k_qkv<<<dim3(16, 32), 512, 0, stream>>>(xn, wt, bq, bk, bv, q, vt);
    k_scores<<<dim3(16, 8, 4), 512, 0, stream>>>(q, k, att);    // frees q,k
    k_softmax<<<8192, 256, 0, stream>>>(att, attb);             // attb over q+k
    k_out<<<dim3(8, 8, 4), 512, 0, stream>>>(attb, vt, out);
}

// Round 9
// 307.855 us; speedup vs baseline: 2.1977x; 1.0284x over previous
//
#include <hip/hip_runtime.h>
#include <stdint.h>

// ---------------------------------------------------------------------------
// SelfAttention: LN -> QKV (bf16 MFMA GEMM) -> S=QK^T/32 -> softmax -> att*V
// B=4, N=2048, D=H=1024. Outputs: att fp32 [4,2048,2048] ++ out fp32 [4,2048,1024]
// R13: TWO-BLOCK-PER-CU GEMM. R6-R9: tile time = LDS-reads + MFMA summed
//   (one 512-thr block, barrier lockstep). R10/R11: fat-wave & forced-4-block
//   die on VGPR file. The untried fix: 2 x 256-thr blocks (4 waves each) per
//   CU -> two INDEPENDENT barrier groups; m114: MFMA-waves and memory-waves
//   on one CU overlap fully (time ~ max, not sum).
//   Enabler: 256x64 tile, BK=64, 2-buf LDS = exactly 81,920 B/block -> 2
//   blocks = 160 KB (trash region dropped; overflow stages clamp kt to NT-1,
//   re-staging a dead buffer with identical data). VGPR ~180 <= 256
//   (launch_bounds(256,2)) -> no spill. R8 half-split pipeline + counted
//   vmw<10> + 16B-seg XOR swizzle (0 conflicts R4-R12) retained.
//   Grids: qkv 48x32=1536 (3 rounds of 512), scores 32x8x4=1024 (2 rounds),
//   out 16x8x4=512 (1 round). Non-GEMM kernels byte-identical to R8 (306.7us).
// ---------------------------------------------------------------------------

typedef __attribute__((ext_vector_type(8))) short short8;   // 8 bf16 (4 VGPRs)
typedef __attribute__((ext_vector_type(4))) float floatx4;  // MFMA acc
typedef __attribute__((ext_vector_type(4))) uint16_t u16x4;

__device__ __forceinline__ uint16_t f2bf(float f) {
    union { float f; uint32_t u; } v; v.f = f;
    uint32_t r = v.u + 0x7fffu + ((v.u >> 16) & 1u);  // RNE
    return (uint16_t)(r >> 16);
}

// async global->LDS, 16B per lane. LDS dest is wave-uniform base + lane*16.
typedef const uint32_t __attribute__((address_space(1)))* gas1_t;
typedef uint32_t __attribute__((address_space(3)))* las3_t;
__device__ __forceinline__ void gload_lds16(const uint16_t* g, uint16_t* l) {
    __builtin_amdgcn_global_load_lds((gas1_t)g, (las3_t)l, 16, 0, 0);
}

__device__ __forceinline__ void s_bar()  { asm volatile("s_barrier" ::: "memory"); }
__device__ __forceinline__ void lgkm0()  { asm volatile("s_waitcnt lgkmcnt(0)" ::: "memory"); }
template<int N> __device__ __forceinline__ void vmw() {
    asm volatile("s_waitcnt vmcnt(%0)" :: "n"(N) : "memory");
}

// ---------------------------------------------------------------------------
// gemm64<EPI>: C = A * Bt^T. A:[M,K] bf16 rm, Bt:[N,K] bf16 rm.
// BM=256, BN=64, BK=64 (2 K-halves). 256 thr = 4 waves (2Mx2N), per-wave
// 128x32: MIW=8, NIW=2, acc 64 VGPR. LDS: 2 x (A 32KB + B 8KB) = 80KB exactly
// -> 2 blocks/CU (the point of this round).
// Staging: thread t covers row t>>3 (0..31, +32/gload), pre-swizzled global
// seg (t&7)^(row&7) -> linear LDS; readers XOR the same -> 0 bank conflicts.
// Per tile: READS(ks1) -> MFMA(ks0) -> lgkm0;bar (WAR: all waves done reading
// cur) -> STGALL(te+2 -> cur buf) -> vmw<10>;bar (RAW: te+1 landed) ->
// READS(next,ks0) -> MFMA(ks1).
//   vmw<10> proof: outstanding <= 10(prev unretired cap) + 10(just issued);
//   drain-to-10 retires all but the newest 10 -> stage(te+1) complete.
// Overflow (kt>=NT): clamp kt=NT-1, target buffer is dead (never read again);
// identical data rewrite -> deterministic, no trash region needed.
// EPI 0: fp32 store * alpha.  EPI 1: fused-qkv bf16 + bias (3072-wide cols
//        de-interleave into q|k|v planes of 8192x1024).
// ---------------------------------------------------------------------------

#define READS(BASE, KS)                                                   \
    { const uint16_t* LBp = (BASE) + ABUF;                                \
      _Pragma("unroll") for (int mi = 0; mi < 8; ++mi)                    \
          Af[mi][KS] = *(const short8*)((BASE) + aoff + mi * 1024 +       \
                                        ((KS) ? ksg1 : ksg0));            \
      _Pragma("unroll") for (int ni = 0; ni < 2; ++ni)                    \
          Bf[ni][KS] = *(const short8*)(LBp + boff + ni * 1024 +          \
                                        ((KS) ? ksg1 : ksg0)); }

#define MFMAS(KS)                                                         \
    __builtin_amdgcn_s_setprio(1);                                        \
    _Pragma("unroll") for (int mi = 0; mi < 8; ++mi)                      \
    _Pragma("unroll") for (int ni = 0; ni < 2; ++ni)                      \
        acc[mi][ni] = __builtin_amdgcn_mfma_f32_16x16x32_bf16(            \
            Af[mi][KS], Bf[ni][KS], acc[mi][ni], 0, 0, 0);                \
    __builtin_amdgcn_s_setprio(0);

template<int EPI>
__device__ __forceinline__ void gemm64(
    const uint16_t* __restrict__ A, const uint16_t* __restrict__ Bt,
    const int K, const int NT, const int m0, const int n0,
    float* __restrict__ Cf, uint16_t* __restrict__ Cb, const int ldc,
    const float* __restrict__ bq, const float* __restrict__ bk,
    const float* __restrict__ bv, const float alpha)
{
    constexpr int ABUF  = 16384;               // A: 256x64 elems (32 KB)
    constexpr int BBUF  = 4096;                // B:  64x64 elems (8 KB)
    constexpr int BUFSZ = ABUF + BBUF;         // 20480 elems = 40 KB
    __shared__ uint16_t sm[2 * BUFSZ];         // 80 KB exactly -> 2 blocks/CU

    const int t = threadIdx.x;

    // ---- staging geometry: thread t covers row t>>3, swizzled 16B-seg ----
    const int srow = t >> 3;                   // 0..31
    const int sseg = (t & 7) ^ (srow & 7);     // pre-swizzled global seg
    const uint16_t* gA = A + (size_t)(m0 + srow) * K + sseg * 8;
    const uint16_t* gB = Bt + (size_t)(n0 + srow) * K + sseg * 8;

    // stage one whole K-tile (10 async gloads, 32 rows / 4KB each)
    auto STGALL = [&](int kt, int bi) {
        kt = (kt < NT) ? kt : (NT - 1);        // clamp: buffer dead, same data
        const size_t ko = (size_t)kt * 64;
        uint16_t* const db = sm + bi * BUFSZ + t * 8;
#pragma unroll
        for (int p = 0; p < 8; ++p)
            gload_lds16(gA + (size_t)(p * 32) * K + ko, db + p * 2048);
#pragma unroll
        for (int p = 0; p < 2; ++p)
            gload_lds16(gB + (size_t)(p * 32) * K + ko, db + ABUF + p * 2048);
    };

    // ---- reader geometry: 4 waves, 2M x 2N, wave tile 128x32 ----
    const int lane = t & 63;
    const int wid  = t >> 6;
    const int wm   = wid >> 1;        // 0..1
    const int wn   = wid & 1;         // 0..1
    const int quad = lane >> 4;
    const int lrow = lane & 15;
    const int swz  = lrow & 7;
    const int ksg0 = (quad ^ swz) * 8;
    const int ksg1 = ((4 + quad) ^ swz) * 8;
    const int aoff = (wm * 128 + lrow) * 64;
    const int boff = (wn * 32 + lrow) * 64;

    floatx4 acc[8][2];
#pragma unroll
    for (int mi = 0; mi < 8; ++mi)
#pragma unroll
        for (int ni = 0; ni < 2; ++ni)
            acc[mi][ni] = floatx4{0.f, 0.f, 0.f, 0.f};

    short8 Af[8][2];
    short8 Bf[2][2];

    // ---- prologue: tiles 0,1 staged; wait tile0; prefetch its ks0 frags ----
    STGALL(0, 0);
    STGALL(1, 1);
    vmw<10>();
    s_bar();
    READS(sm, 0);

    for (int te = 0; te < NT; ++te) {
        const uint16_t* LA  = sm + (te & 1) * BUFSZ;
        const uint16_t* LAn = sm + ((te + 1) & 1) * BUFSZ;

        READS(LA, 1);                          // ks1 frags of te (issue only)
        MFMAS(0);                              // ks0: operands prefetched
        lgkm0();                               // own reads of LA complete
        s_bar();                               // all waves done reading (WAR)
        STGALL(te + 2, te & 1);                // re-stage current buffer
        vmw<10>();                             // stage(te+1) landed (RAW)
        s_bar();
        READS(LAn, 0);                         // ks0 frags of te+1 (issue only)
        MFMAS(1);                              // ks1 of te; covers the reads
    }

    vmw<0>();  // drain trailing clamped stages

    // ---- epilogue: C/D layout col=lane&15, row=quad*4+reg [m89/m91] ----
    const int rbase = m0 + wm * 128 + quad * 4;
    const int cbase = n0 + wn * 32 + lrow;

    if constexpr (EPI == 1) {
        float bc[2];
#pragma unroll
        for (int ni = 0; ni < 2; ++ni) {
            const int col = cbase + ni * 16;
            const int z = col >> 10;
            const float* bp = (z == 0) ? bq : ((z == 1) ? bk : bv);
            bc[ni] = bp[col & 1023];
        }
#pragma unroll
        for (int mi = 0; mi < 8; ++mi) {
#pragma unroll
            for (int ni = 0; ni < 2; ++ni) {
                const int row = rbase + mi * 16;
                const int col = cbase + ni * 16;
                const int z = col >> 10, h = col & 1023;
#pragma unroll
                for (int r = 0; r < 4; ++r)
                    Cb[(size_t)z * 8388608 + (size_t)(row + r) * 1024 + h] =
                        f2bf(acc[mi][ni][r] + bc[ni]);
            }
        }
    } else {
#pragma unroll
        for (int mi = 0; mi < 8; ++mi) {
#pragma unroll
            for (int ni = 0; ni < 2; ++ni) {
                const int row = rbase + mi * 16;
                const int col = cbase + ni * 16;
#pragma unroll
                for (int r = 0; r < 4; ++r)
                    Cf[(size_t)(row + r) * ldc + col] = acc[mi][ni][r] * alpha;
            }
        }
    }
}

// q|k|v = xn @ [wq|wk|wv]^T + bias, one GEMM M=8192 N=3072 K=1024.
__global__ __launch_bounds__(256, 2) void k_qkv(
    const uint16_t* __restrict__ xn, const uint16_t* __restrict__ wt,
    const float* __restrict__ bq, const float* __restrict__ bk,
    const float* __restrict__ bv, uint16_t* __restrict__ qkv)
{
    // grid (48, 32) = 1536 blocks -> 3 uniform rounds of 512; XCD-bijective
    const int flat = blockIdx.y * 48 + blockIdx.x;
    const int s = (flat & 7) * 192 + (flat >> 3);
    const int bx = s % 48, by = s / 48;
    gemm64<1>(xn, wt, 1024, 16, by * 256, bx * 64,
              nullptr, qkv, 0, bq, bk, bv, 0.f);
}

// S = q @ k^T * (1/32), fp32 into d_out att region. grid 1024 = 2 rounds.
__global__ __launch_bounds__(256, 2) void k_scores(
    const uint16_t* __restrict__ q, const uint16_t* __restrict__ k,
    float* __restrict__ S)
{
    const int flat = (blockIdx.z * 8 + blockIdx.y) * 32 + blockIdx.x;
    const int s = (flat & 7) * 128 + (flat >> 3);       // 1024-bijective
    const int x = s & 31, y = (s >> 5) & 7, z = s >> 8;
    gemm64<0>(q + (size_t)z * 2048 * 1024, k + (size_t)z * 2048 * 1024,
              1024, 16, y * 256, x * 64,
              S + (size_t)z * 2048 * 2048, nullptr, 2048,
              nullptr, nullptr, nullptr, 0.03125f);
}

// out = att_bf16 @ vt^T, fp32. K=2048, grid 512 = 1 round of 2/CU.
__global__ __launch_bounds__(256, 2) void k_out(
    const uint16_t* __restrict__ attb, const uint16_t* __restrict__ vt,
    float* __restrict__ out)
{
    const int flat = (blockIdx.z * 8 + blockIdx.y) * 16 + blockIdx.x;
    const int s = (flat & 7) * 64 + (flat >> 3);        // 512-bijective
    const int x = s & 15, y = (s >> 4) & 7, z = s >> 7;
    gemm64<0>(attb + (size_t)z * 2048 * 2048, vt + (size_t)z * 1024 * 2048,
              2048, 32, y * 256, x * 64,
              out + (size_t)z * 2048 * 1024, nullptr, 1024,
              nullptr, nullptr, nullptr, 1.0f);
}

// ---------------------------------------------------------------------------
// LayerNorm rows of x[8192][1024] -> bf16 xn
// ---------------------------------------------------------------------------
__global__ __launch_bounds__(256) void k_ln(
    const float* __restrict__ x, const float* __restrict__ lw,
    const float* __restrict__ lb, uint16_t* __restrict__ xn)
{
    const int row = blockIdx.x;
    const int t = threadIdx.x;
    const float* xr = x + (size_t)row * 1024;
    const float4 xv = ((const float4*)xr)[t];
    float s  = xv.x + xv.y + xv.z + xv.w;
    float s2 = xv.x * xv.x + xv.y * xv.y + xv.z * xv.z + xv.w * xv.w;
#pragma unroll
    for (int off = 32; off > 0; off >>= 1) {
        s  += __shfl_xor(s, off);
        s2 += __shfl_xor(s2, off);
    }
    __shared__ float ps[4], ps2[4];
    const int w = t >> 6, lane = t & 63;
    if (lane == 0) { ps[w] = s; ps2[w] = s2; }
    __syncthreads();
    s  = ps[0] + ps[1] + ps[2] + ps[3];
    s2 = ps2[0] + ps2[1] + ps2[2] + ps2[3];
    const float mu  = s * (1.f / 1024.f);
    const float var = s2 * (1.f / 1024.f) - mu * mu;
    const float rs  = rsqrtf(var + 1e-5f);
    const float4 wv = ((const float4*)lw)[t];
    const float4 bv = ((const float4*)lb)[t];
    u16x4 o;
    o.x = f2bf((xv.x - mu) * rs * wv.x + bv.x);
    o.y = f2bf((xv.y - mu) * rs * wv.y + bv.y);
    o.z = f2bf((xv.z - mu) * rs * wv.z + bv.z);
    o.w = f2bf((xv.w - mu) * rs * wv.w + bv.w);
    ((u16x4*)(xn + (size_t)row * 1024))[t] = o;
}

// ---------------------------------------------------------------------------
// Transpose + cast weights: w[1024][1024] fp32 -> wt[1024][1024] bf16 (wt[h][d])
// ---------------------------------------------------------------------------
__global__ void k_wt(const float* __restrict__ wq, const float* __restrict__ wk,
                     const float* __restrict__ wv, uint16_t* __restrict__ wt)
{
    __shared__ float tile[32][33];
    const int z = blockIdx.z;
    const float* W = (z == 0) ? wq : ((z == 1) ? wk : wv);
    uint16_t* T = wt + (size_t)z * 1024 * 1024;
    const int c0 = blockIdx.x * 32, r0 = blockIdx.y * 32;
    const int tx = threadIdx.x, ty = threadIdx.y;  // (32,8)
#pragma unroll
    for (int i = 0; i < 4; i++)
        tile[ty + 8 * i][tx] = W[(size_t)(r0 + ty + 8 * i) * 1024 + c0 + tx];
    __syncthreads();
#pragma unroll
    for (int i = 0; i < 4; i++)
        T[(size_t)(c0 + ty + 8 * i) * 1024 + r0 + tx] = f2bf(tile[tx][ty + 8 * i]);
}

// ---------------------------------------------------------------------------
// Transpose v bf16 [2048][1024] -> vt [1024][2048] per batch.
// ---------------------------------------------------------------------------
__global__ __launch_bounds__(256) void k_vt(
    const uint16_t* __restrict__ v, uint16_t* __restrict__ vt)
{
    __shared__ uint16_t tile[64][68];
    const int b = blockIdx.z;
    const uint16_t* V = v + (size_t)b * 2048 * 1024;
    uint16_t* T = vt + (size_t)b * 1024 * 2048;
    const int h0 = blockIdx.x * 64, t0 = blockIdx.y * 64;
    const int t = threadIdx.x;
    const int rr = t >> 4;
    const int cc = (t & 15) * 4;
#pragma unroll
    for (int i = 0; i < 4; i++) {
        const int tok = rr + 16 * i;
        *(u16x4*)&tile[tok][cc] =
            *(const u16x4*)&V[(size_t)(t0 + tok) * 1024 + h0 + cc];
    }
    __syncthreads();
#pragma unroll
    for (int i = 0; i < 4; i++) {
        const int h = rr + 16 * i;
        u16x4 o;
        o.x = tile[cc + 0][h];
        o.y = tile[cc + 1][h];
        o.z = tile[cc + 2][h];
        o.w = tile[cc + 3][h];
        *(u16x4*)&T[(size_t)(h0 + h) * 2048 + t0 + cc] = o;
    }
}

// ---------------------------------------------------------------------------
// Row softmax over S[8192][2048] fp32 (in place) + bf16 copy for the PV GEMM
// ---------------------------------------------------------------------------
__global__ __launch_bounds__(256) void k_softmax(
    float* __restrict__ S, uint16_t* __restrict__ attb)
{
    const size_t row = blockIdx.x;
    float* p = S + row * 2048;
    const int t = threadIdx.x;
    float4 a = ((float4*)p)[2 * t];
    float4 b = ((float4*)p)[2 * t + 1];
    float m = fmaxf(fmaxf(fmaxf(a.x, a.y), fmaxf(a.z, a.w)),
                    fmaxf(fmaxf(b.x, b.y), fmaxf(b.z, b.w)));
#pragma unroll
    for (int off = 32; off > 0; off >>= 1) m = fmaxf(m, __shfl_xor(m, off));
    __shared__ float pm[4], pl[4];
    const int w = t >> 6, lane = t & 63;
    if (lane == 0) pm[w] = m;
    __syncthreads();
    m = fmaxf(fmaxf(pm[0], pm[1]), fmaxf(pm[2], pm[3]));

    a.x = __expf(a.x - m); a.y = __expf(a.y - m);
    a.z = __expf(a.z - m); a.w = __expf(a.w - m);
    b.x = __expf(b.x - m); b.y = __expf(b.y - m);
    b.z = __expf(b.z - m); b.w = __expf(b.w - m);
    float s = a.x + a.y + a.z + a.w + b.x + b.y + b.z + b.w;
#pragma unroll
    for (int off = 32; off > 0; off >>= 1) s += __shfl_xor(s, off);
    if (lane == 0) pl[w] = s;
    __syncthreads();
    s = pl[0] + pl[1] + pl[2] + pl[3];
    const float inv = 1.f / s;

    a.x *= inv; a.y *= inv; a.z *= inv; a.w *= inv;
    b.x *= inv; b.y *= inv; b.z *= inv; b.w *= inv;
    ((float4*)p)[2 * t]     = a;
    ((float4*)p)[2 * t + 1] = b;

    uint16_t* q = attb + row * 2048 + t * 8;
    u16x4 o0, o1;
    o0.x = f2bf(a.x); o0.y = f2bf(a.y); o0.z = f2bf(a.z); o0.w = f2bf(a.w);
    o1.x = f2bf(b.x); o1.y = f2bf(b.y); o1.z = f2bf(b.z); o1.w = f2bf(b.w);
    ((u16x4*)q)[0] = o0;
    ((u16x4*)q)[1] = o1;
}

// ---------------------------------------------------------------------------
extern "C" void kernel_launch(void* const* d_in, const int* in_sizes, int n_in,
                              void* d_out, int out_size, void* d_ws, size_t ws_size,
                              hipStream_t stream)
{
    const float* x  = (const float*)d_in[0];
    const float* wq = (const float*)d_in[1];
    const float* bq = (const float*)d_in[2];
    const float* wk = (const float*)d_in[3];
    const float* bk = (const float*)d_in[4];
    const float* wv = (const float*)d_in[5];
    const float* bv = (const float*)d_in[6];
    const float* lw = (const float*)d_in[7];
    const float* lb = (const float*)d_in[8];

    float* att = (float*)d_out;                         // [4][2048][2048] = 64 MB
    float* out = (float*)d_out + (size_t)16777216;      // [4][2048][1024] = 32 MB

    // Scratch inside d_out's att region (dead until k_scores writes all of it):
    uint16_t* xn = (uint16_t*)d_out;                    // 8,388,608 elems (16.8 MB)
    uint16_t* wt = (uint16_t*)d_out + (size_t)8388608;  // 3,145,728 elems (6.3 MB)

    // ws layout (uint16 elems), exactly q+k+v = 25,165,824 elems = 50,331,648 B:
    //   [0, 8M)    q   -> dead after k_scores -> reused as vt
    //   [8M, 16M)  k   -> dead after k_scores ┐
    //   [16M, 24M) v   -> dead after k_vt     ┴-> reused as attb (16M elems)
    uint16_t* ws   = (uint16_t*)d_ws;
    uint16_t* q    = ws;
    uint16_t* k    = ws + (size_t)8388608;
    uint16_t* v    = ws + (size_t)2 * 8388608;
    uint16_t* vt   = ws;                                // overlays dead q
    uint16_t* attb = ws + (size_t)8388608;              // overlays dead k+v
    uint16_t* qkv  = q;

    if (ws_size < (size_t)50331648) return;  // OOB guard: fail clean, not crash

    k_ln<<<8192, 256, 0, stream>>>(x, lw, lb, xn);
    k_wt<<<dim3(32, 32, 3), dim3(32, 8), 0, stream>>>(wq, wk, wv, wt);
    k_qkv<<<dim3(48, 32), 256, 0, stream>>>(xn, wt, bq, bk, bv, qkv);
    k_scores<<<dim3(32, 8, 4), 256, 0, stream>>>(q, k, att);    // frees q,k
    k_vt<<<dim3(16, 32, 4), 256, 0, stream>>>(v, vt);           // vt over dead q
    k_softmax<<<8192, 256, 0, stream>>>(att, attb);             // attb over dead k+v
    k_out<<<dim3(16, 8, 4), 256, 0, stream>>>(attb, vt, out);
}

// Round 10
// 294.629 us; speedup vs baseline: 2.2964x; 1.0449x over previous
//
#include <hip/hip_runtime.h>
#include <stdint.h>

// ---------------------------------------------------------------------------
// SelfAttention: LN -> QKV (bf16 MFMA GEMM) -> S=QK^T/32 -> softmax -> att*V
// B=4, N=2048, D=H=1024. Outputs: att fp32 [4,2048,2048] ++ out fp32 [4,2048,1024]
// R14: consolidation on the measured optimum. GEMM bodies/grids/ws = R8
//   byte-identical (best total 306.7us). Design space closed by measurement:
//   - 1 big block: barrier lockstep, LDS-reads+MFMA summed (R6-R9, 5 schedules)
//   - 2 blocks/CU: needs <=80KB -> smaller tiles -> staging amplification
//     (R13: FETCH 59.6->92MB, net loss)
//   - fat waves / B-direct: VGPR file / spill bound (R10, R11)
//   Only change vs R8: k_ln + k_wt merged into k_prep (proven R11/R12).
//   Launches 7 -> 6: prep, qkv, scores, vt, softmax, out.
// ---------------------------------------------------------------------------

typedef __attribute__((ext_vector_type(8))) short short8;   // 8 bf16 (4 VGPRs)
typedef __attribute__((ext_vector_type(4))) float floatx4;  // MFMA acc
typedef __attribute__((ext_vector_type(4))) uint16_t u16x4;

__device__ __forceinline__ uint16_t f2bf(float f) {
    union { float f; uint32_t u; } v; v.f = f;
    uint32_t r = v.u + 0x7fffu + ((v.u >> 16) & 1u);  // RNE
    return (uint16_t)(r >> 16);
}

// async global->LDS, 16B per lane. LDS dest is wave-uniform base + lane*16.
typedef const uint32_t __attribute__((address_space(1)))* gas1_t;
typedef uint32_t __attribute__((address_space(3)))* las3_t;
__device__ __forceinline__ void gload_lds16(const uint16_t* g, uint16_t* l) {
    __builtin_amdgcn_global_load_lds((gas1_t)g, (las3_t)l, 16, 0, 0);
}

__device__ __forceinline__ void s_bar()  { asm volatile("s_barrier" ::: "memory"); }
__device__ __forceinline__ void lgkm0()  { asm volatile("s_waitcnt lgkmcnt(0)" ::: "memory"); }
template<int N> __device__ __forceinline__ void vmw() {
    asm volatile("s_waitcnt vmcnt(%0)" :: "n"(N) : "memory");
}

// ---------------------------------------------------------------------------
// gemm_core<BN,EPI>: C = A * Bt^T. A:[M,K] bf16 rm, Bt:[N,K] bf16 rm. BM=256.
// 512 thr = 8 waves. BN=192: 2Mx4N waves (per-wave 128x48), 2-buf LDS.
// BN=128: 4Mx2N waves (per-wave 64x64), 3-buf LDS, 1 barrier/tile.
// BK=64 split into two K-halves ks0/ks1 (ksg0/ksg1 swizzled segs).
// 16B-seg XOR swizzle (phys_seg = seg ^ (row&7)) via pre-swizzled global src +
// linear LDS dest; readers XOR the same -> 0 bank conflicts (proven R4-R13).
// Hazards per tile: WAR = lgkm0 (+bar for 2-buf) before re-staging a read
// buffer; RAW = counted vmw<OPS> + bar before reading next tile's buffer.
// EPI 0: fp32 store * alpha.  EPI 1: fused-qkv bf16 + bias, 3072-wide cols
//        de-interleave into q|k|v planes of 8192x1024.
// ---------------------------------------------------------------------------

#define READS(BASE, KS)                                                   \
    { const uint16_t* LBp = (BASE) + ABUF;                                \
      _Pragma("unroll") for (int mi = 0; mi < MIW; ++mi)                  \
          Af[mi][KS] = *(const short8*)((BASE) + aoff + mi * 1024 +       \
                                        ((KS) ? ksg1 : ksg0));            \
      _Pragma("unroll") for (int ni = 0; ni < NIW; ++ni)                  \
          Bf[ni][KS] = *(const short8*)(LBp + boff + ni * 1024 +          \
                                        ((KS) ? ksg1 : ksg0)); }

#define MFMAS(KS)                                                         \
    __builtin_amdgcn_s_setprio(1);                                        \
    _Pragma("unroll") for (int mi = 0; mi < MIW; ++mi)                    \
    _Pragma("unroll") for (int ni = 0; ni < NIW; ++ni)                    \
        acc[mi][ni] = __builtin_amdgcn_mfma_f32_16x16x32_bf16(            \
            Af[mi][KS], Bf[ni][KS], acc[mi][ni], 0, 0, 0);                \
    __builtin_amdgcn_s_setprio(0);

template<int BN, int EPI>
__device__ __forceinline__ void gemm_core(
    const uint16_t* __restrict__ A, const uint16_t* __restrict__ Bt,
    const int K, const int NT, const int m0, const int n0,
    float* __restrict__ Cf, uint16_t* __restrict__ Cb, const int ldc,
    const float* __restrict__ bq, const float* __restrict__ bk,
    const float* __restrict__ bv, const float alpha)
{
    constexpr int ABUF  = 256 * 64;            // 16384 elems
    constexpr int BP    = BN / 64;             // B stage passes (3,2)
    constexpr int BBUF  = BN * 64;
    constexpr int BUFSZ = ABUF + BBUF;
    constexpr int OPS   = 4 + BP;              // stage ops per K-tile
    constexpr int NBUF  = (BN == 128) ? 3 : 2;
    constexpr int WAVES_N = (BN == 128) ? 2 : 4;
    constexpr int MIW  = (BN == 128) ? 4 : 8;  // mi frags per wave
    constexpr int NIW  = BN / (16 * WAVES_N);  // ni frags (4 or 3)
    __shared__ uint16_t sm[NBUF * BUFSZ + 4096];
    uint16_t* const trash = sm + NBUF * BUFSZ;

    const int t = threadIdx.x;

    // ---- staging geometry ----
    const int srow = t >> 3;                  // 0..63
    const int sseg = (t & 7) ^ (srow & 7);    // pre-swizzled global 16B-seg
    const uint16_t* gA = A + (size_t)(m0 + srow) * K + sseg * 8;
    const uint16_t* gB = Bt + (size_t)(n0 + srow) * K + sseg * 8;

    // stage one whole K-tile (OPS async gloads); kt>=NT -> trash (never read)
    auto STGALL = [&](int kt, int bi) {
        const int live = kt < NT;
        const size_t ko = (size_t)(live ? kt : 0) * 64;
        uint16_t* const db = sm + bi * BUFSZ + t * 8;
        uint16_t* const tr = trash + t * 8;
#pragma unroll
        for (int p = 0; p < 4; ++p)
            gload_lds16(gA + (size_t)(p * 64) * K + ko,
                        live ? (db + p * 4096) : tr);
#pragma unroll
        for (int p = 0; p < BP; ++p)
            gload_lds16(gB + (size_t)(p * 64) * K + ko,
                        live ? (db + ABUF + p * 4096) : tr);
    };

    // ---- reader geometry ----
    const int lane = t & 63;
    const int wid  = t >> 6;
    const int wm   = wid / WAVES_N;
    const int wn   = wid % WAVES_N;
    const int quad = lane >> 4;
    const int lrow = lane & 15;
    const int swz  = lrow & 7;
    const int ksg0 = (quad ^ swz) * 8;
    const int ksg1 = ((4 + quad) ^ swz) * 8;
    const int aoff = (wm * (16 * MIW) + lrow) * 64;
    const int boff = (wn * (16 * NIW) + lrow) * 64;

    floatx4 acc[MIW][NIW];
#pragma unroll
    for (int mi = 0; mi < MIW; ++mi)
#pragma unroll
        for (int ni = 0; ni < NIW; ++ni)
            acc[mi][ni] = floatx4{0.f, 0.f, 0.f, 0.f};

    short8 Af[MIW][2];
    short8 Bf[NIW][2];

    // ---- prologue: tiles 0,1 staged; wait tile0; prefetch its ks0 frags ----
    STGALL(0, 0);
    STGALL(1, 1);
    vmw<OPS>();
    s_bar();
    READS(sm, 0);

    int bcur = 0, bstage = 2;  // BN==128 3-buffer rotation only
    for (int te = 0; te < NT; ++te) {
        const uint16_t* LA;
        const uint16_t* LAn;
        if constexpr (BN == 128) {
            LA = sm + bcur * BUFSZ;
            const int bnext = (bcur == 2) ? 0 : bcur + 1;
            LAn = sm + bnext * BUFSZ;
            STGALL(te + 2, bstage);            // free buffer: no WAR wait
        } else {
            LA  = sm + (te & 1) * BUFSZ;
            LAn = sm + ((te + 1) & 1) * BUFSZ;
        }

        READS(LA, 1);                          // ks1 frags of te (issue only)
        MFMAS(0);                              // ks0: operands prefetched
        lgkm0();                               // own reads of LA complete (WAR)
        if constexpr (BN != 128) {
            s_bar();                           // all waves done reading bi
            STGALL(te + 2, te & 1);            // re-stage current buffer
        }
        vmw<OPS>();                            // te+1's stages landed (RAW)
        s_bar();
        READS(LAn, 0);                         // ks0 frags of te+1 (issue only)
        MFMAS(1);                              // ks1 of te; covers the reads

        if constexpr (BN == 128) {
            bcur   = (bcur == 2) ? 0 : bcur + 1;
            bstage = (bstage == 2) ? 0 : bstage + 1;
        }
    }

    vmw<0>();  // drain clamped trash stages

    // ---- epilogue: C/D layout col=lane&15, row=quad*4+reg [m89/m91] ----
    const int rbase = m0 + wm * (16 * MIW) + quad * 4;
    const int cbase = n0 + wn * (16 * NIW) + lrow;

    if constexpr (EPI == 1) {
        float bc[NIW];
#pragma unroll
        for (int ni = 0; ni < NIW; ++ni) {
            const int col = cbase + ni * 16;
            const int z = col >> 10;
            const float* bp = (z == 0) ? bq : ((z == 1) ? bk : bv);
            bc[ni] = bp[col & 1023];
        }
#pragma unroll
        for (int mi = 0; mi < MIW; ++mi) {
#pragma unroll
            for (int ni = 0; ni < NIW; ++ni) {
                const int row = rbase + mi * 16;
                const int col = cbase + ni * 16;
                const int z = col >> 10, h = col & 1023;
#pragma unroll
                for (int r = 0; r < 4; ++r)
                    Cb[(size_t)z * 8388608 + (size_t)(row + r) * 1024 + h] =
                        f2bf(acc[mi][ni][r] + bc[ni]);
            }
        }
    } else {
#pragma unroll
        for (int mi = 0; mi < MIW; ++mi) {
#pragma unroll
            for (int ni = 0; ni < NIW; ++ni) {
                const int row = rbase + mi * 16;
                const int col = cbase + ni * 16;
#pragma unroll
                for (int r = 0; r < 4; ++r)
                    Cf[(size_t)(row + r) * ldc + col] = acc[mi][ni][r] * alpha;
            }
        }
    }
}

// q|k|v = xn @ [wq|wk|wv]^T + bias, one GEMM M=8192 N=3072 K=1024, BN=192.
__global__ __launch_bounds__(512, 2) void k_qkv(
    const uint16_t* __restrict__ xn, const uint16_t* __restrict__ wt,
    const float* __restrict__ bq, const float* __restrict__ bk,
    const float* __restrict__ bv, uint16_t* __restrict__ qkv)
{
    // grid (16, 32) = 512 blocks -> 2 uniform rounds; bijective XCD swizzle
    const int flat = blockIdx.y * 16 + blockIdx.x;
    const int s = (flat & 7) * 64 + (flat >> 3);
    const int bx = s & 15, by = s >> 4;
    gemm_core<192, 1>(xn, wt, 1024, 16, by * 256, bx * 192,
                      nullptr, qkv, 0, bq, bk, bv, 0.f);
}

// S = q @ k^T * (1/32), fp32 into d_out att region. BN=128, 512 blocks.
__global__ __launch_bounds__(512, 2) void k_scores(
    const uint16_t* __restrict__ q, const uint16_t* __restrict__ k,
    float* __restrict__ S)
{
    const int flat = (blockIdx.z * 8 + blockIdx.y) * 16 + blockIdx.x;
    const int s = (flat & 7) * 64 + (flat >> 3);        // 512-bijective
    const int x = s & 15, y = (s >> 4) & 7, z = s >> 7;
    gemm_core<128, 0>(q + (size_t)z * 2048 * 1024, k + (size_t)z * 2048 * 1024,
                      1024, 16, y * 256, x * 128,
                      S + (size_t)z * 2048 * 2048, nullptr, 2048,
                      nullptr, nullptr, nullptr, 0.03125f);
}

// out = att_bf16 @ vt^T, fp32. BN=128, K=2048, grid 256 = 1/CU, 3-buf LDS.
__global__ __launch_bounds__(512, 2) void k_out(
    const uint16_t* __restrict__ attb, const uint16_t* __restrict__ vt,
    float* __restrict__ out)
{
    const int flat = blockIdx.z * 64 + blockIdx.y * 8 + blockIdx.x;
    const int s = (flat & 7) * 32 + (flat >> 3);        // 256-bijective
    const int z = s >> 6, y = (s >> 3) & 7, x = s & 7;
    gemm_core<128, 0>(attb + (size_t)z * 2048 * 2048, vt + (size_t)z * 1024 * 2048,
                      2048, 32, y * 256, x * 128,
                      out + (size_t)z * 2048 * 1024, nullptr, 1024,
                      nullptr, nullptr, nullptr, 1.0f);
}

// ---------------------------------------------------------------------------
// k_prep: blocks [0,8192) = LayerNorm rows x[8192][1024] -> bf16 xn;
//         blocks [8192,11264) = weight transpose+cast fp32 -> bf16 wt[h][d].
// ---------------------------------------------------------------------------
__global__ __launch_bounds__(256) void k_prep(
    const float* __restrict__ x, const float* __restrict__ lw,
    const float* __restrict__ lb, uint16_t* __restrict__ xn,
    const float* __restrict__ wq, const float* __restrict__ wk,
    const float* __restrict__ wv, uint16_t* __restrict__ wt)
{
    const int t = threadIdx.x;
    if (blockIdx.x < 8192) {
        const int row = blockIdx.x;
        const float* xr = x + (size_t)row * 1024;
        const float4 xv = ((const float4*)xr)[t];
        float s  = xv.x + xv.y + xv.z + xv.w;
        float s2 = xv.x * xv.x + xv.y * xv.y + xv.z * xv.z + xv.w * xv.w;
#pragma unroll
        for (int off = 32; off > 0; off >>= 1) {
            s  += __shfl_xor(s, off);
            s2 += __shfl_xor(s2, off);
        }
        __shared__ float ps[4], ps2[4];
        const int w = t >> 6, lane = t & 63;
        if (lane == 0) { ps[w] = s; ps2[w] = s2; }
        __syncthreads();
        s  = ps[0] + ps[1] + ps[2] + ps[3];
        s2 = ps2[0] + ps2[1] + ps2[2] + ps2[3];
        const float mu  = s * (1.f / 1024.f);
        const float var = s2 * (1.f / 1024.f) - mu * mu;
        const float rs  = rsqrtf(var + 1e-5f);
        const float4 wv4 = ((const float4*)lw)[t];
        const float4 bv4 = ((const float4*)lb)[t];
        u16x4 o;
        o.x = f2bf((xv.x - mu) * rs * wv4.x + bv4.x);
        o.y = f2bf((xv.y - mu) * rs * wv4.y + bv4.y);
        o.z = f2bf((xv.z - mu) * rs * wv4.z + bv4.z);
        o.w = f2bf((xv.w - mu) * rs * wv4.w + bv4.w);
        ((u16x4*)(xn + (size_t)row * 1024))[t] = o;
    } else {
        __shared__ float tile[32][33];
        const int bid = blockIdx.x - 8192;
        const int z = bid >> 10;                 // 0..2
        const int rem = bid & 1023;
        const int c0 = (rem & 31) * 32, r0 = (rem >> 5) * 32;
        const float* W = (z == 0) ? wq : ((z == 1) ? wk : wv);
        uint16_t* T = wt + (size_t)z * 1024 * 1024;
        const int tx = t & 31, ty = t >> 5;      // (32,8)
#pragma unroll
        for (int i = 0; i < 4; i++)
            tile[ty + 8 * i][tx] = W[(size_t)(r0 + ty + 8 * i) * 1024 + c0 + tx];
        __syncthreads();
#pragma unroll
        for (int i = 0; i < 4; i++)
            T[(size_t)(c0 + ty + 8 * i) * 1024 + r0 + tx] = f2bf(tile[tx][ty + 8 * i]);
    }
}

// ---------------------------------------------------------------------------
// Transpose v bf16 [2048][1024] -> vt [1024][2048] per batch.
// ---------------------------------------------------------------------------
__global__ __launch_bounds__(256) void k_vt(
    const uint16_t* __restrict__ v, uint16_t* __restrict__ vt)
{
    __shared__ uint16_t tile[64][68];
    const int b = blockIdx.z;
    const uint16_t* V = v + (size_t)b * 2048 * 1024;
    uint16_t* T = vt + (size_t)b * 1024 * 2048;
    const int h0 = blockIdx.x * 64, t0 = blockIdx.y * 64;
    const int t = threadIdx.x;
    const int rr = t >> 4;
    const int cc = (t & 15) * 4;
#pragma unroll
    for (int i = 0; i < 4; i++) {
        const int tok = rr + 16 * i;
        *(u16x4*)&tile[tok][cc] =
            *(const u16x4*)&V[(size_t)(t0 + tok) * 1024 + h0 + cc];
    }
    __syncthreads();
#pragma unroll
    for (int i = 0; i < 4; i++) {
        const int h = rr + 16 * i;
        u16x4 o;
        o.x = tile[cc + 0][h];
        o.y = tile[cc + 1][h];
        o.z = tile[cc + 2][h];
        o.w = tile[cc + 3][h];
        *(u16x4*)&T[(size_t)(h0 + h) * 2048 + t0 + cc] = o;
    }
}

// ---------------------------------------------------------------------------
// Row softmax over S[8192][2048] fp32 (in place) + bf16 copy for the PV GEMM
// ---------------------------------------------------------------------------
__global__ __launch_bounds__(256) void k_softmax(
    float* __restrict__ S, uint16_t* __restrict__ attb)
{
    const size_t row = blockIdx.x;
    float* p = S + row * 2048;
    const int t = threadIdx.x;
    float4 a = ((float4*)p)[2 * t];
    float4 b = ((float4*)p)[2 * t + 1];
    float m = fmaxf(fmaxf(fmaxf(a.x, a.y), fmaxf(a.z, a.w)),
                    fmaxf(fmaxf(b.x, b.y), fmaxf(b.z, b.w)));
#pragma unroll
    for (int off = 32; off > 0; off >>= 1) m = fmaxf(m, __shfl_xor(m, off));
    __shared__ float pm[4], pl[4];
    const int w = t >> 6, lane = t & 63;
    if (lane == 0) pm[w] = m;
    __syncthreads();
    m = fmaxf(fmaxf(pm[0], pm[1]), fmaxf(pm[2], pm[3]));

    a.x = __expf(a.x - m); a.y = __expf(a.y - m);
    a.z = __expf(a.z - m); a.w = __expf(a.w - m);
    b.x = __expf(b.x - m); b.y = __expf(b.y - m);
    b.z = __expf(b.z - m); b.w = __expf(b.w - m);
    float s = a.x + a.y + a.z + a.w + b.x + b.y + b.z + b.w;
#pragma unroll
    for (int off = 32; off > 0; off >>= 1) s += __shfl_xor(s, off);
    if (lane == 0) pl[w] = s;
    __syncthreads();
    s = pl[0] + pl[1] + pl[2] + pl[3];
    const float inv = 1.f / s;

    a.x *= inv; a.y *= inv; a.z *= inv; a.w *= inv;
    b.x *= inv; b.y *= inv; b.z *= inv; b.w *= inv;
    ((float4*)p)[2 * t]     = a;
    ((float4*)p)[2 * t + 1] = b;

    uint16_t* q = attb + row * 2048 + t * 8;
    u16x4 o0, o1;
    o0.x = f2bf(a.x); o0.y = f2bf(a.y); o0.z = f2bf(a.z); o0.w = f2bf(a.w);
    o1.x = f2bf(b.x); o1.y = f2bf(b.y); o1.z = f2bf(b.z); o1.w = f2bf(b.w);
    ((u16x4*)q)[0] = o0;
    ((u16x4*)q)[1] = o1;
}

// ---------------------------------------------------------------------------
extern "C" void kernel_launch(void* const* d_in, const int* in_sizes, int n_in,
                              void* d_out, int out_size, void* d_ws, size_t ws_size,
                              hipStream_t stream)
{
    const float* x  = (const float*)d_in[0];
    const float* wq = (const float*)d_in[1];
    const float* bq = (const float*)d_in[2];
    const float* wk = (const float*)d_in[3];
    const float* bk = (const float*)d_in[4];
    const float* wv = (const float*)d_in[5];
    const float* bv = (const float*)d_in[6];
    const float* lw = (const float*)d_in[7];
    const float* lb = (const float*)d_in[8];

    float* att = (float*)d_out;                         // [4][2048][2048] = 64 MB
    float* out = (float*)d_out + (size_t)16777216;      // [4][2048][1024] = 32 MB

    // Scratch inside d_out's att region (dead until k_scores writes all of it):
    uint16_t* xn = (uint16_t*)d_out;                    // 8,388,608 elems (16.8 MB)
    uint16_t* wt = (uint16_t*)d_out + (size_t)8388608;  // 3,145,728 elems (6.3 MB)

    // ws layout (uint16 elems), exactly q+k+v = 25,165,824 elems = 50,331,648 B:
    //   [0, 8M)    q   -> dead after k_scores -> reused as vt
    //   [8M, 16M)  k   -> dead after k_scores ┐
    //   [16M, 24M) v   -> dead after k_vt     ┴-> reused as attb (16M elems)
    uint16_t* ws   = (uint16_t*)d_ws;
    uint16_t* q    = ws;
    uint16_t* k    = ws + (size_t)8388608;
    uint16_t* v    = ws + (size_t)2 * 8388608;
    uint16_t* vt   = ws;                                // overlays dead q
    uint16_t* attb = ws + (size_t)8388608;              // overlays dead k+v
    uint16_t* qkv  = q;

    if (ws_size < (size_t)50331648) return;  // OOB guard: fail clean, not crash

    k_prep<<<8192 + 3072, 256, 0, stream>>>(x, lw, lb, xn, wq, wk, wv, wt);
    k_qkv<<<dim3(16, 32), 512, 0, stream>>>(xn, wt, bq, bk, bv, qkv);
    k_scores<<<dim3(16, 8, 4), 512, 0, stream>>>(q, k, att);    // frees q,k
    k_vt<<<dim3(16, 32, 4), 256, 0, stream>>>(v, vt);           // vt over dead q
    k_softmax<<<8192, 256, 0, stream>>>(att, attb);             // attb over dead k+v
    k_out<<<dim3(8, 8, 4), 512, 0, stream>>>(attb, vt, out);
}